// Round 18
// baseline (1192.442 us; speedup 1.0000x reference)
//
#include <hip/hip_runtime.h>
#include <hip/hip_bf16.h>
#include <stdint.h>

#define NB 8
#define NS 256
#define NH 512
#define NG 1024
#define NV 256
#define NL 24
#define NC 320
#define NT 2048
#define EPSF 1e-5f

typedef __bf16 bf16;
typedef bf16 bf16x8 __attribute__((ext_vector_type(8)));
typedef float f32x4 __attribute__((ext_vector_type(4)));

__device__ __forceinline__ bf16 f2bf(float f) {
    uint32_t u = __builtin_bit_cast(uint32_t, f);
    u += 0x7FFFu + ((u >> 16) & 1u);
    uint16_t b = (uint16_t)(u >> 16);
    return __builtin_bit_cast(bf16, b);
}
__device__ __forceinline__ uint16_t bfbits(float f) {
    uint32_t u = __builtin_bit_cast(uint32_t, f);
    u += 0x7FFFu + ((u >> 16) & 1u);
    return (uint16_t)(u >> 16);
}

__device__ __forceinline__ void gload16(const void* g, void* l) {
    __builtin_amdgcn_global_load_lds(
        (const __attribute__((address_space(1))) void*)g,
        (__attribute__((address_space(3))) void*)l,
        16, 0, 0);
}

// stage 64-row x 64-elem bf16 tile; LDS chunk XOR-swizzled via pre-swizzled src
__device__ __forceinline__ void stage64(
    const bf16* __restrict__ src, int ldk, bf16* lds, int wv_, int lane)
{
    #pragma unroll
    for (int j = 0; j < 2; ++j) {
        const int gI = wv_*2 + j;
        const int r  = gI*8 + (lane >> 3);
        const int ch = (lane & 7) ^ (lane >> 3);
        gload16(src + (size_t)r*ldk + ch*8, lds + gI*512);
    }
}
__device__ __forceinline__ const bf16x8* fragp(const bf16* lds, int row, int ch) {
    return (const bf16x8*)(lds + row*64 + ((ch ^ (row & 7)) << 3));
}

#define MFMA(a,b,c) __builtin_amdgcn_mfma_f32_16x16x32_bf16(a, b, c, 0, 0, 0)

// ---------------- init: convert ALL weights (wv,wg,wo,stem,head) in ONE dispatch
__global__ __launch_bounds__(256) void k_cvt_all(
    const float* __restrict__ wv, const float* __restrict__ wg,
    const float* __restrict__ wo, const float* __restrict__ sw,
    const float* __restrict__ hw, bf16* __restrict__ dwv,
    bf16* __restrict__ dwg, bf16* __restrict__ dwo,
    bf16* __restrict__ dsw, bf16* __restrict__ dhw)
{
    const int n1 = NL*NG*NH/8;          // 1572864
    const int n4 = NH*NC/8;             // 20480
    const int n5 = NV*NH/8;             // 16384
    const int N = 3*n1 + n4 + n5;
    for (int i = blockIdx.x*256 + threadIdx.x; i < N; i += gridDim.x*256) {
        const float* s; bf16* d; int j;
        if (i < n1)            { s = wv; d = dwv; j = i; }
        else if (i < 2*n1)     { s = wg; d = dwg; j = i - n1; }
        else if (i < 3*n1)     { s = wo; d = dwo; j = i - 2*n1; }
        else if (i < 3*n1+n4)  { s = sw; d = dsw; j = i - 3*n1; }
        else                   { s = hw; d = dhw; j = i - 3*n1 - n4; }
        const float* sp = s + (size_t)j*8;
        float4 v0 = *(const float4*)&sp[0];
        float4 v1 = *(const float4*)&sp[4];
        bf16x8 t;
        t[0] = f2bf(v0.x); t[1] = f2bf(v0.y); t[2] = f2bf(v0.z); t[3] = f2bf(v0.w);
        t[4] = f2bf(v1.x); t[5] = f2bf(v1.y); t[6] = f2bf(v1.z); t[7] = f2bf(v1.w);
        *(bf16x8*)&d[(size_t)j*8] = t;
    }
}

// ---------------- init: transpose mix weights [l][c][pj] f32 -> [l][pj][c] bf16
__global__ __launch_bounds__(256) void k_trw(
    const float* __restrict__ wl, const float* __restrict__ wg,
    bf16* __restrict__ wlT, bf16* __restrict__ wgT)
{
    __shared__ bf16 Ls[64*72];
    const int pj0 = blockIdx.x*64, c0 = blockIdx.y*64;
    const int z = blockIdx.z, l = z >> 1;
    const float* src = (z & 1) ? wg : wl;
    bf16* dst = (z & 1) ? wgT : wlT;
    src += (size_t)l*NH*256;
    dst += (size_t)l*256*NH;
    const int tid = threadIdx.x;
    #pragma unroll
    for (int e = 0; e < 16; ++e) {
        int idx = e*256 + tid;
        int cl = idx >> 6, pj = idx & 63;
        Ls[pj*72 + cl] = f2bf(src[(size_t)(c0 + cl)*256 + pj0 + pj]);
    }
    __syncthreads();
    #pragma unroll
    for (int e = 0; e < 2; ++e) {
        int idx = e*256 + tid;
        int row = idx >> 3, ch8 = idx & 7;
        *(bf16x8*)&dst[(size_t)(pj0 + row)*NH + c0 + ch8*8] =
            *(const bf16x8*)&Ls[row*72 + ch8*8];
    }
}

// ---------------- init: x[b][c][s] f32 -> xT[b*256+s][c] bf16
__global__ __launch_bounds__(256) void k_trx(
    const float* __restrict__ x, bf16* __restrict__ xT)
{
    __shared__ bf16 Ls[64*72];
    const int s0 = blockIdx.x*64, c0 = blockIdx.y*64, b = blockIdx.z;
    const int tid = threadIdx.x;
    #pragma unroll
    for (int e = 0; e < 16; ++e) {
        int idx = tid + e*256;
        int c = idx >> 6, s = idx & 63;
        Ls[s*72 + c] = f2bf(x[(size_t)(b*NC + c0 + c)*NS + s0 + s]);
    }
    __syncthreads();
    #pragma unroll
    for (int e = 0; e < 2; ++e) {
        int idx = tid + e*256;
        int s = idx >> 3, ch = idx & 7;
        *(bf16x8*)&xT[(size_t)(b*NS + s0 + s)*NC + c0 + ch*8] =
            *(const bf16x8*)&Ls[s*72 + ch*8];
    }
}

// ---------------- stem GEMM: h[t,o] = xT[t,:] . wb[o,:]
__global__ __launch_bounds__(256) void k_stem_b(
    const bf16* __restrict__ xT, const bf16* __restrict__ wb,
    float* __restrict__ h)
{
    __shared__ __align__(16) bf16 As[2][4096], Bs[2][4096];
    __shared__ float Cs[64*66];
    const int t0 = blockIdx.x*64, n0 = blockIdx.y*64;
    const int tid = threadIdx.x, lane = tid & 63, wv_ = tid >> 6;
    const int wm = wv_ >> 1, wn = wv_ & 1;
    const int fr = lane & 15, kq = lane >> 4;
    const bf16* Ag = xT + (size_t)t0*NC;
    const bf16* Bg = wb + (size_t)n0*NC;
    f32x4 acc[2][2] = {};
    stage64(Ag, NC, As[0], wv_, lane);
    stage64(Bg, NC, Bs[0], wv_, lane);
    __syncthreads();
    const int NIT = NC/64;
    for (int it = 0; it < NIT; ++it) {
        const int cur = it & 1;
        if (it + 1 < NIT) {
            stage64(Ag + (it+1)*64, NC, As[cur^1], wv_, lane);
            stage64(Bg + (it+1)*64, NC, Bs[cur^1], wv_, lane);
        }
        #pragma unroll
        for (int kk = 0; kk < 2; ++kk) {
            const int ch = kk*4 + kq;
            bf16x8 a0 = *fragp(As[cur], wm*32 + fr,      ch);
            bf16x8 a1 = *fragp(As[cur], wm*32 + 16 + fr, ch);
            bf16x8 b0 = *fragp(Bs[cur], wn*32 + fr,      ch);
            bf16x8 b1 = *fragp(Bs[cur], wn*32 + 16 + fr, ch);
            acc[0][0] = MFMA(a0, b0, acc[0][0]);
            acc[0][1] = MFMA(a0, b1, acc[0][1]);
            acc[1][0] = MFMA(a1, b0, acc[1][0]);
            acc[1][1] = MFMA(a1, b1, acc[1][1]);
        }
        __syncthreads();
    }
    const int row4 = (lane >> 4)*4, col = lane & 15;
    #pragma unroll
    for (int mi = 0; mi < 2; ++mi)
      #pragma unroll
      for (int ni = 0; ni < 2; ++ni)
        #pragma unroll
        for (int r = 0; r < 4; ++r)
            Cs[(wm*32 + mi*16 + row4 + r)*66 + wn*32 + ni*16 + col] = acc[mi][ni][r];
    __syncthreads();
    const int rr = tid >> 2, c16 = (tid & 3)*16;
    float* dst = &h[(size_t)(t0 + rr)*NH + n0 + c16];
    #pragma unroll
    for (int i = 0; i < 16; ++i) dst[i] = Cs[rr*66 + c16 + i];
}

// ---------------- unified mix with block-local RMS norm, split output-tokens
template<int STR, bool FFN>
__global__ __launch_bounds__(256) void k_mix2(
    float* __restrict__ h, const bf16* __restrict__ wT,
    const float* __restrict__ rmsw, const float* __restrict__ alpha_p,
    const float* __restrict__ rmsw_ffn, bf16* __restrict__ a_bf)
{
    __shared__ float raw[16][512];
    __shared__ float red[4][16];
    __shared__ float rstdL[16];
    const int b = blockIdx.x, gi = blockIdx.y, ph = blockIdx.z;
    const int base = b*NS + (STR == 1 ? gi*16 : gi);
    const int tid = threadIdx.x, lane = tid & 63, wid = tid >> 6;
    #pragma unroll
    for (int e = 0; e < 8; ++e) {
        int idx = e*256 + tid;
        int k = idx >> 7, c4 = idx & 127;
        *(float4*)&raw[k][c4*4] = *(const float4*)&h[(size_t)(base + k*STR)*NH + c4*4];
    }
    __syncthreads();
    const int c0 = tid*2;
    float u0[16], u1[16], part[16];
    #pragma unroll
    for (int k = 0; k < 16; ++k) {
        float A = raw[k][c0], B = raw[k][c0+1];
        u0[k] = A; u1[k] = B; part[k] = A*A + B*B;
    }
    #pragma unroll
    for (int m = 1; m < 64; m <<= 1)
        #pragma unroll
        for (int k = 0; k < 16; ++k) part[k] += __shfl_xor(part[k], m, 64);
    if (lane == 0) {
        #pragma unroll
        for (int k = 0; k < 16; ++k) red[wid][k] = part[k];
    }
    __syncthreads();
    if (tid < 16)
        rstdL[tid] = rsqrtf((red[0][tid]+red[1][tid]+red[2][tid]+red[3][tid])*(1.f/NH) + EPSF);
    __syncthreads();
    #pragma unroll
    for (int k = 0; k < 16; ++k) { u0[k] *= rstdL[k]; u1[k] *= rstdL[k]; }
    const float al = *alpha_p;
    const float rc0 = rmsw[c0]*al, rc1 = rmsw[c0+1]*al;
    const uint32_t* wrow = (const uint32_t*)wT + tid;   // dword = channels (2t,2t+1)
    float hn0[8], hn1[8];
    #pragma unroll
    for (int pp = 0; pp < 8; ++pp) {
        const int p = ph*8 + pp;
        float a0 = 0.f, a1 = 0.f;
        #pragma unroll
        for (int k = 0; k < 16; ++k) {
            uint32_t wz = wrow[(p*16 + k)*256];
            float w0 = __builtin_bit_cast(float, wz << 16);
            float w1 = __builtin_bit_cast(float, wz & 0xffff0000u);
            a0 += w0*u0[k]; a1 += w1*u1[k];
        }
        hn0[pp] = raw[p][c0]   + rc0*a0;
        hn1[pp] = raw[p][c0+1] + rc1*a1;
        float2 o; o.x = hn0[pp]; o.y = hn1[pp];
        *(float2*)&h[(size_t)(base + p*STR)*NH + c0] = o;
    }
    if constexpr (FFN) {
        float p2[8];
        #pragma unroll
        for (int pp = 0; pp < 8; ++pp) p2[pp] = hn0[pp]*hn0[pp] + hn1[pp]*hn1[pp];
        #pragma unroll
        for (int m = 1; m < 64; m <<= 1)
            #pragma unroll
            for (int pp = 0; pp < 8; ++pp) p2[pp] += __shfl_xor(p2[pp], m, 64);
        __syncthreads();
        if (lane == 0) {
            #pragma unroll
            for (int pp = 0; pp < 8; ++pp) red[wid][pp] = p2[pp];
        }
        __syncthreads();
        if (tid < 8)
            rstdL[tid] = rsqrtf((red[0][tid]+red[1][tid]+red[2][tid]+red[3][tid])*(1.f/NH) + EPSF);
        __syncthreads();
        const float rf0 = rmsw_ffn[c0], rf1 = rmsw_ffn[c0+1];
        #pragma unroll
        for (int pp = 0; pp < 8; ++pp) {
            const int p = ph*8 + pp;
            float r = rstdL[pp];
            uint32_t pk = ((uint32_t)bfbits(hn1[pp]*r*rf1) << 16) | bfbits(hn0[pp]*r*rf0);
            *(uint32_t*)&a_bf[(size_t)(base + p*STR)*NH + c0] = pk;
        }
    }
}

// ---------------- head norm: a[t,c] = bf16(h[t,c]*rstd(t)*rmsw[c])
__global__ __launch_bounds__(256) void k_norm2(
    const float* __restrict__ h, const float* __restrict__ rmsw,
    bf16* __restrict__ a)
{
    const int t = blockIdx.x*4 + (threadIdx.x >> 6);
    const int lane = threadIdx.x & 63;
    const int c8 = lane*8;
    const float* src = &h[(size_t)t*NH + c8];
    float4 h0 = *(const float4*)&src[0];
    float4 h1 = *(const float4*)&src[4];
    float ss = h0.x*h0.x + h0.y*h0.y + h0.z*h0.z + h0.w*h0.w
             + h1.x*h1.x + h1.y*h1.y + h1.z*h1.z + h1.w*h1.w;
    #pragma unroll
    for (int m = 1; m < 64; m <<= 1) ss += __shfl_xor(ss, m, 64);
    const float rstd = rsqrtf(ss*(1.f/NH) + EPSF);
    float4 w0 = *(const float4*)&rmsw[c8];
    float4 w1 = *(const float4*)&rmsw[c8 + 4];
    bf16x8 o;
    o[0] = f2bf(h0.x*rstd*w0.x); o[1] = f2bf(h0.y*rstd*w0.y);
    o[2] = f2bf(h0.z*rstd*w0.z); o[3] = f2bf(h0.w*rstd*w0.w);
    o[4] = f2bf(h1.x*rstd*w1.x); o[5] = f2bf(h1.y*rstd*w1.y);
    o[6] = f2bf(h1.z*rstd*w1.z); o[7] = f2bf(h1.w*rstd*w1.w);
    *(bf16x8*)&a[(size_t)t*NH + c8] = o;
}

// ---------------- mlp in (BM=128): g = silu(wv . a) * (wg . a)   (bf16 out)
// grid (16,16); 4 waves 2Mx2N; wave tile 64x32 per GEMM; LDS 64KB, Gs aliased
__global__ __launch_bounds__(256) void k_mlp_in(
    const bf16* __restrict__ a, const bf16* __restrict__ wvl,
    const bf16* __restrict__ wgl, bf16* __restrict__ g)
{
    __shared__ __align__(16) char sm[65536];
    bf16* As  = (bf16*)sm;              // [2][8192] = 32KB (128 rows x 64 K, dbuf)
    bf16* B1s = (bf16*)(sm + 32768);    // [2][4096] = 16KB
    bf16* B3s = (bf16*)(sm + 49152);    // [2][4096] = 16KB
    bf16* Gs  = (bf16*)sm;              // epilogue alias: 128*72*2 = 18KB
    const int t0 = blockIdx.x*128, n0 = blockIdx.y*64;
    const int tid = threadIdx.x, lane = tid & 63, wv_ = tid >> 6;
    const int wm = wv_ >> 1, wn = wv_ & 1;
    const int fr = lane & 15, kq = lane >> 4;
    const bf16* Ag = a   + (size_t)t0*NH;
    const bf16* Vg = wvl + (size_t)n0*NH;
    const bf16* Gg = wgl + (size_t)n0*NH;
    f32x4 acc1[4][2] = {}, acc3[4][2] = {};
    stage64(Ag, NH, As, wv_, lane);
    stage64(Ag + (size_t)64*NH, NH, As + 4096, wv_, lane);
    stage64(Vg, NH, B1s, wv_, lane);
    stage64(Gg, NH, B3s, wv_, lane);
    __syncthreads();
    const int NIT = NH/64;   // 8
    for (int it = 0; it < NIT; ++it) {
        const int cur = it & 1;
        if (it + 1 < NIT) {
            const bf16* Ak = Ag + (it+1)*64;
            stage64(Ak, NH, As + (cur^1)*8192, wv_, lane);
            stage64(Ak + (size_t)64*NH, NH, As + (cur^1)*8192 + 4096, wv_, lane);
            stage64(Vg + (it+1)*64, NH, B1s + (cur^1)*4096, wv_, lane);
            stage64(Gg + (it+1)*64, NH, B3s + (cur^1)*4096, wv_, lane);
        }
        #pragma unroll
        for (int kk = 0; kk < 2; ++kk) {
            const int ch = kk*4 + kq;
            bf16x8 am[4];
            #pragma unroll
            for (int mi = 0; mi < 4; ++mi)
                am[mi] = *fragp(As + cur*8192, wm*64 + mi*16 + fr, ch);
            bf16x8 u0 = *fragp(B1s + cur*4096, wn*32 + fr,      ch);
            bf16x8 u1 = *fragp(B1s + cur*4096, wn*32 + 16 + fr, ch);
            bf16x8 v0 = *fragp(B3s + cur*4096, wn*32 + fr,      ch);
            bf16x8 v1 = *fragp(B3s + cur*4096, wn*32 + 16 + fr, ch);
            #pragma unroll
            for (int mi = 0; mi < 4; ++mi) {
                acc1[mi][0] = MFMA(am[mi], u0, acc1[mi][0]);
                acc1[mi][1] = MFMA(am[mi], u1, acc1[mi][1]);
                acc3[mi][0] = MFMA(am[mi], v0, acc3[mi][0]);
                acc3[mi][1] = MFMA(am[mi], v1, acc3[mi][1]);
            }
        }
        __syncthreads();
    }
    const int row4 = (lane >> 4)*4, col = lane & 15;
    #pragma unroll
    for (int mi = 0; mi < 4; ++mi)
      #pragma unroll
      for (int ni = 0; ni < 2; ++ni)
        #pragma unroll
        for (int r = 0; r < 4; ++r) {
            float xv = acc1[mi][ni][r];
            float gl = (xv / (1.f + __expf(-xv))) * acc3[mi][ni][r];
            Gs[(wm*64 + mi*16 + row4 + r)*72 + wn*32 + ni*16 + col] = f2bf(gl);
        }
    __syncthreads();
    const int rr = tid >> 1, c32 = (tid & 1)*32;
    #pragma unroll
    for (int j = 0; j < 4; ++j)
        *(bf16x8*)&g[(size_t)(t0 + rr)*NG + n0 + c32 + j*8] =
            *(const bf16x8*)&Gs[rr*72 + c32 + j*8];
}

// ---------------- mlp out (BM=64, 256 blocks): h += alpha * (wo . g)
__global__ __launch_bounds__(256) void k_mlp_out(
    const bf16* __restrict__ g, const bf16* __restrict__ wol,
    const float* __restrict__ alpha_p, float* __restrict__ h)
{
    __shared__ __align__(16) bf16 As[2][4096], Bs[2][4096];
    __shared__ float Cs[64*66];
    const int t0 = blockIdx.x*64, n0 = blockIdx.y*64;
    const int tid = threadIdx.x, lane = tid & 63, wv_ = tid >> 6;
    const int wm = wv_ >> 1, wn = wv_ & 1;
    const int fr = lane & 15, kq = lane >> 4;
    const bf16* Ag = g   + (size_t)t0*NG;
    const bf16* Bg = wol + (size_t)n0*NG;
    f32x4 acc[2][2] = {};
    stage64(Ag, NG, As[0], wv_, lane);
    stage64(Bg, NG, Bs[0], wv_, lane);
    __syncthreads();
    const int NIT = NG/64;
    for (int it = 0; it < NIT; ++it) {
        const int cur = it & 1;
        if (it + 1 < NIT) {
            stage64(Ag + (it+1)*64, NG, As[cur^1], wv_, lane);
            stage64(Bg + (it+1)*64, NG, Bs[cur^1], wv_, lane);
        }
        #pragma unroll
        for (int kk = 0; kk < 2; ++kk) {
            const int ch = kk*4 + kq;
            bf16x8 a0 = *fragp(As[cur], wm*32 + fr,      ch);
            bf16x8 a1 = *fragp(As[cur], wm*32 + 16 + fr, ch);
            bf16x8 b0 = *fragp(Bs[cur], wn*32 + fr,      ch);
            bf16x8 b1 = *fragp(Bs[cur], wn*32 + 16 + fr, ch);
            acc[0][0] = MFMA(a0, b0, acc[0][0]);
            acc[0][1] = MFMA(a0, b1, acc[0][1]);
            acc[1][0] = MFMA(a1, b0, acc[1][0]);
            acc[1][1] = MFMA(a1, b1, acc[1][1]);
        }
        __syncthreads();
    }
    const int row4 = (lane >> 4)*4, col = lane & 15;
    #pragma unroll
    for (int mi = 0; mi < 2; ++mi)
      #pragma unroll
      for (int ni = 0; ni < 2; ++ni)
        #pragma unroll
        for (int r = 0; r < 4; ++r)
            Cs[(wm*32 + mi*16 + row4 + r)*66 + wn*32 + ni*16 + col] = acc[mi][ni][r];
    __syncthreads();
    const float am = *alpha_p;
    const int rr = tid >> 2, c16 = (tid & 3)*16;
    float* dst = &h[(size_t)(t0 + rr)*NH + n0 + c16];
    #pragma unroll
    for (int i = 0; i < 4; ++i) {
        float4 hv = *(const float4*)&dst[i*4];
        float4 cv = *(const float4*)&Cs[rr*66 + c16 + i*4];
        hv.x += am*cv.x; hv.y += am*cv.y; hv.z += am*cv.z; hv.w += am*cv.w;
        *(float4*)&dst[i*4] = hv;
    }
}

// ---------------- head: logits = scale * head_w . a
__global__ __launch_bounds__(256) void k_head(
    const bf16* __restrict__ a, const bf16* __restrict__ hw,
    const float* __restrict__ scale_p, float* __restrict__ out)
{
    __shared__ __align__(16) bf16 As[2][4096], Bs[2][4096];
    __shared__ float Ls[64*66];
    const int t0 = blockIdx.x*64, n0 = blockIdx.y*64;
    const int tid = threadIdx.x, lane = tid & 63, wv_ = tid >> 6;
    const int wm = wv_ >> 1, wn = wv_ & 1;
    const int fr = lane & 15, kq = lane >> 4;
    const bf16* Ag = a  + (size_t)t0*NH;
    const bf16* Bg = hw + (size_t)n0*NH;
    f32x4 acc[2][2] = {};
    stage64(Ag, NH, As[0], wv_, lane);
    stage64(Bg, NH, Bs[0], wv_, lane);
    __syncthreads();
    const int NIT = NH/64;
    for (int it = 0; it < NIT; ++it) {
        const int cur = it & 1;
        if (it + 1 < NIT) {
            stage64(Ag + (it+1)*64, NH, As[cur^1], wv_, lane);
            stage64(Bg + (it+1)*64, NH, Bs[cur^1], wv_, lane);
        }
        #pragma unroll
        for (int kk = 0; kk < 2; ++kk) {
            const int ch = kk*4 + kq;
            bf16x8 a0 = *fragp(As[cur], wm*32 + fr,      ch);
            bf16x8 a1 = *fragp(As[cur], wm*32 + 16 + fr, ch);
            bf16x8 b0 = *fragp(Bs[cur], wn*32 + fr,      ch);
            bf16x8 b1 = *fragp(Bs[cur], wn*32 + 16 + fr, ch);
            acc[0][0] = MFMA(a0, b0, acc[0][0]);
            acc[0][1] = MFMA(a0, b1, acc[0][1]);
            acc[1][0] = MFMA(a1, b0, acc[1][0]);
            acc[1][1] = MFMA(a1, b1, acc[1][1]);
        }
        __syncthreads();
    }
    const float sc = *scale_p;
    const int row4 = (lane >> 4)*4, col = lane & 15;
    #pragma unroll
    for (int mi = 0; mi < 2; ++mi)
      #pragma unroll
      for (int ni = 0; ni < 2; ++ni)
        #pragma unroll
        for (int r = 0; r < 4; ++r)
            Ls[(wm*32 + mi*16 + row4 + r)*66 + wn*32 + ni*16 + col] = sc * acc[mi][ni][r];
    __syncthreads();
    const int vv = tid >> 2, s16 = (tid & 3)*16;
    const int b = t0 >> 8, s0 = t0 & 255;
    float* dst = &out[((size_t)(b*NV + n0 + vv))*NS + s0 + s16];
    #pragma unroll
    for (int i = 0; i < 16; ++i) dst[i] = Ls[(s16 + i)*66 + vv];
}

extern "C" void kernel_launch(void* const* d_in, const int* in_sizes, int n_in,
                              void* d_out, int out_size, void* d_ws, size_t ws_size,
                              hipStream_t stream) {
    const float* x          = (const float*)d_in[0];
    const float* stem_w     = (const float*)d_in[1];
    const float* rms_local  = (const float*)d_in[2];
    const float* rms_global = (const float*)d_in[3];
    const float* rms_ffn    = (const float*)d_in[4];
    const float* alpha_local  = (const float*)d_in[5];
    const float* alpha_global = (const float*)d_in[6];
    const float* alpha_mlp    = (const float*)d_in[7];
    const float* w_local    = (const float*)d_in[8];
    const float* w_global   = (const float*)d_in[9];
    const float* wv         = (const float*)d_in[10];
    const float* wg         = (const float*)d_in[11];
    const float* wo         = (const float*)d_in[12];
    const float* head_rms   = (const float*)d_in[13];
    const float* head_scale = (const float*)d_in[14];
    const float* head_w     = (const float*)d_in[15];
    float* out = (float*)d_out;

    char* ws = (char*)d_ws;
    const size_t MB = 1024*1024;
    float* h    = (float*)(ws);                 // 4MB
    bf16*  g    = (bf16*)(ws + 4*MB);           // 4MB
    bf16*  a_bf = (bf16*)(ws + 8*MB);           // 2MB
    bf16* xT      = (bf16*)(ws + 16*MB);        // 1.31MB
    bf16* stem_wb = (bf16*)(ws + 18*MB);        // 0.33MB
    bf16* head_wb = (bf16*)(ws + 19*MB);        // 0.26MB
    bf16* wlT     = (bf16*)(ws + 20*MB);        // 6MB
    bf16* wgT     = (bf16*)(ws + 26*MB);        // 6MB
    bf16* wv_b    = (bf16*)(ws + 32*MB);        // 24MB
    bf16* wg_b    = (bf16*)(ws + 56*MB);        // 24MB
    bf16* wo_b    = (bf16*)(ws + 80*MB);        // 24MB -> end 104MB

    // init: 3 dispatches
    k_cvt_all<<<4096, 256, 0, stream>>>(wv, wg, wo, stem_w, head_w,
                                        wv_b, wg_b, wo_b, stem_wb, head_wb);
    k_trw<<<dim3(4, 8, 48), 256, 0, stream>>>(w_local, w_global, wlT, wgT);
    k_trx<<<dim3(4, 5, 8), 256, 0, stream>>>(x, xT);

    k_stem_b<<<dim3(32, 8), 256, 0, stream>>>(xT, stem_wb, h);

    for (int l = 0; l < NL; ++l) {
        k_mix2<1, false><<<dim3(NB, 16, 2), 256, 0, stream>>>(
            h, wlT + (size_t)l*256*NH, rms_local + l*NH, alpha_local + l,
            nullptr, nullptr);
        k_mix2<16, true><<<dim3(NB, 16, 2), 256, 0, stream>>>(
            h, wgT + (size_t)l*256*NH, rms_global + l*NH, alpha_global + l,
            rms_ffn + l*NH, a_bf);
        k_mlp_in<<<dim3(16, 16), 256, 0, stream>>>(
            a_bf, wv_b + (size_t)l*NG*NH, wg_b + (size_t)l*NG*NH, g);
        k_mlp_out<<<dim3(32, 8), 256, 0, stream>>>(
            g, wo_b + (size_t)l*NH*NG, alpha_mlp + l, h);
    }
    k_norm2<<<512, 256, 0, stream>>>(h, head_rms, a_bf);
    k_head<<<dim3(32, 4), 256, 0, stream>>>(a_bf, head_wb, head_scale, out);
}

// Round 19
// 1132.714 us; speedup vs baseline: 1.0527x; 1.0527x over previous
//
#include <hip/hip_runtime.h>
#include <hip/hip_bf16.h>
#include <stdint.h>

#define NB 8
#define NS 256
#define NH 512
#define NG 1024
#define NV 256
#define NL 24
#define NC 320
#define NT 2048
#define EPSF 1e-5f

typedef __bf16 bf16;
typedef bf16 bf16x8 __attribute__((ext_vector_type(8)));
typedef float f32x4 __attribute__((ext_vector_type(4)));

__device__ __forceinline__ bf16 f2bf(float f) {
    uint32_t u = __builtin_bit_cast(uint32_t, f);
    u += 0x7FFFu + ((u >> 16) & 1u);
    uint16_t b = (uint16_t)(u >> 16);
    return __builtin_bit_cast(bf16, b);
}
__device__ __forceinline__ uint16_t bfbits(float f) {
    uint32_t u = __builtin_bit_cast(uint32_t, f);
    u += 0x7FFFu + ((u >> 16) & 1u);
    return (uint16_t)(u >> 16);
}

__device__ __forceinline__ void gload16(const void* g, void* l) {
    __builtin_amdgcn_global_load_lds(
        (const __attribute__((address_space(1))) void*)g,
        (__attribute__((address_space(3))) void*)l,
        16, 0, 0);
}

// stage 64-row x 64-elem bf16 tile; LDS chunk XOR-swizzled via pre-swizzled src
__device__ __forceinline__ void stage64(
    const bf16* __restrict__ src, int ldk, bf16* lds, int wv_, int lane)
{
    #pragma unroll
    for (int j = 0; j < 2; ++j) {
        const int gI = wv_*2 + j;
        const int r  = gI*8 + (lane >> 3);
        const int ch = (lane & 7) ^ (lane >> 3);
        gload16(src + (size_t)r*ldk + ch*8, lds + gI*512);
    }
}
__device__ __forceinline__ const bf16x8* fragp(const bf16* lds, int row, int ch) {
    return (const bf16x8*)(lds + row*64 + ((ch ^ (row & 7)) << 3));
}

#define MFMA(a,b,c) __builtin_amdgcn_mfma_f32_16x16x32_bf16(a, b, c, 0, 0, 0)

// ---------------- init: convert ALL weights (wv,wg,wo,stem,head) in ONE dispatch
__global__ __launch_bounds__(256) void k_cvt_all(
    const float* __restrict__ wv, const float* __restrict__ wg,
    const float* __restrict__ wo, const float* __restrict__ sw,
    const float* __restrict__ hw, bf16* __restrict__ dwv,
    bf16* __restrict__ dwg, bf16* __restrict__ dwo,
    bf16* __restrict__ dsw, bf16* __restrict__ dhw)
{
    const int n1 = NL*NG*NH/8;          // 1572864
    const int n4 = NH*NC/8;             // 20480
    const int n5 = NV*NH/8;             // 16384
    const int N = 3*n1 + n4 + n5;
    for (int i = blockIdx.x*256 + threadIdx.x; i < N; i += gridDim.x*256) {
        const float* s; bf16* d; int j;
        if (i < n1)            { s = wv; d = dwv; j = i; }
        else if (i < 2*n1)     { s = wg; d = dwg; j = i - n1; }
        else if (i < 3*n1)     { s = wo; d = dwo; j = i - 2*n1; }
        else if (i < 3*n1+n4)  { s = sw; d = dsw; j = i - 3*n1; }
        else                   { s = hw; d = dhw; j = i - 3*n1 - n4; }
        const float* sp = s + (size_t)j*8;
        float4 v0 = *(const float4*)&sp[0];
        float4 v1 = *(const float4*)&sp[4];
        bf16x8 t;
        t[0] = f2bf(v0.x); t[1] = f2bf(v0.y); t[2] = f2bf(v0.z); t[3] = f2bf(v0.w);
        t[4] = f2bf(v1.x); t[5] = f2bf(v1.y); t[6] = f2bf(v1.z); t[7] = f2bf(v1.w);
        *(bf16x8*)&d[(size_t)j*8] = t;
    }
}

// ---------------- init: transpose mix weights [l][c][pj] f32 -> [l][pj][c] bf16
__global__ __launch_bounds__(256) void k_trw(
    const float* __restrict__ wl, const float* __restrict__ wg,
    bf16* __restrict__ wlT, bf16* __restrict__ wgT)
{
    __shared__ bf16 Ls[64*72];
    const int pj0 = blockIdx.x*64, c0 = blockIdx.y*64;
    const int z = blockIdx.z, l = z >> 1;
    const float* src = (z & 1) ? wg : wl;
    bf16* dst = (z & 1) ? wgT : wlT;
    src += (size_t)l*NH*256;
    dst += (size_t)l*256*NH;
    const int tid = threadIdx.x;
    #pragma unroll
    for (int e = 0; e < 16; ++e) {
        int idx = e*256 + tid;
        int cl = idx >> 6, pj = idx & 63;
        Ls[pj*72 + cl] = f2bf(src[(size_t)(c0 + cl)*256 + pj0 + pj]);
    }
    __syncthreads();
    #pragma unroll
    for (int e = 0; e < 2; ++e) {
        int idx = e*256 + tid;
        int row = idx >> 3, ch8 = idx & 7;
        *(bf16x8*)&dst[(size_t)(pj0 + row)*NH + c0 + ch8*8] =
            *(const bf16x8*)&Ls[row*72 + ch8*8];
    }
}

// ---------------- init: x[b][c][s] f32 -> xT[b*256+s][c] bf16
__global__ __launch_bounds__(256) void k_trx(
    const float* __restrict__ x, bf16* __restrict__ xT)
{
    __shared__ bf16 Ls[64*72];
    const int s0 = blockIdx.x*64, c0 = blockIdx.y*64, b = blockIdx.z;
    const int tid = threadIdx.x;
    #pragma unroll
    for (int e = 0; e < 16; ++e) {
        int idx = tid + e*256;
        int c = idx >> 6, s = idx & 63;
        Ls[s*72 + c] = f2bf(x[(size_t)(b*NC + c0 + c)*NS + s0 + s]);
    }
    __syncthreads();
    #pragma unroll
    for (int e = 0; e < 2; ++e) {
        int idx = tid + e*256;
        int s = idx >> 3, ch = idx & 7;
        *(bf16x8*)&xT[(size_t)(b*NS + s0 + s)*NC + c0 + ch*8] =
            *(const bf16x8*)&Ls[s*72 + ch*8];
    }
}

// ---------------- stem GEMM: h[t,o] = xT[t,:] . wb[o,:]
__global__ __launch_bounds__(256) void k_stem_b(
    const bf16* __restrict__ xT, const bf16* __restrict__ wb,
    float* __restrict__ h)
{
    __shared__ __align__(16) bf16 As[2][4096], Bs[2][4096];
    __shared__ float Cs[64*66];
    const int t0 = blockIdx.x*64, n0 = blockIdx.y*64;
    const int tid = threadIdx.x, lane = tid & 63, wv_ = tid >> 6;
    const int wm = wv_ >> 1, wn = wv_ & 1;
    const int fr = lane & 15, kq = lane >> 4;
    const bf16* Ag = xT + (size_t)t0*NC;
    const bf16* Bg = wb + (size_t)n0*NC;
    f32x4 acc[2][2] = {};
    stage64(Ag, NC, As[0], wv_, lane);
    stage64(Bg, NC, Bs[0], wv_, lane);
    __syncthreads();
    const int NIT = NC/64;
    for (int it = 0; it < NIT; ++it) {
        const int cur = it & 1;
        if (it + 1 < NIT) {
            stage64(Ag + (it+1)*64, NC, As[cur^1], wv_, lane);
            stage64(Bg + (it+1)*64, NC, Bs[cur^1], wv_, lane);
        }
        #pragma unroll
        for (int kk = 0; kk < 2; ++kk) {
            const int ch = kk*4 + kq;
            bf16x8 a0 = *fragp(As[cur], wm*32 + fr,      ch);
            bf16x8 a1 = *fragp(As[cur], wm*32 + 16 + fr, ch);
            bf16x8 b0 = *fragp(Bs[cur], wn*32 + fr,      ch);
            bf16x8 b1 = *fragp(Bs[cur], wn*32 + 16 + fr, ch);
            acc[0][0] = MFMA(a0, b0, acc[0][0]);
            acc[0][1] = MFMA(a0, b1, acc[0][1]);
            acc[1][0] = MFMA(a1, b0, acc[1][0]);
            acc[1][1] = MFMA(a1, b1, acc[1][1]);
        }
        __syncthreads();
    }
    const int row4 = (lane >> 4)*4, col = lane & 15;
    #pragma unroll
    for (int mi = 0; mi < 2; ++mi)
      #pragma unroll
      for (int ni = 0; ni < 2; ++ni)
        #pragma unroll
        for (int r = 0; r < 4; ++r)
            Cs[(wm*32 + mi*16 + row4 + r)*66 + wn*32 + ni*16 + col] = acc[mi][ni][r];
    __syncthreads();
    const int rr = tid >> 2, c16 = (tid & 3)*16;
    float* dst = &h[(size_t)(t0 + rr)*NH + n0 + c16];
    #pragma unroll
    for (int i = 0; i < 16; ++i) dst[i] = Cs[rr*66 + c16 + i];
}

// ---------------- unified mix with block-local RMS norm, split output-tokens
template<int STR, bool FFN>
__global__ __launch_bounds__(256) void k_mix2(
    float* __restrict__ h, const bf16* __restrict__ wT,
    const float* __restrict__ rmsw, const float* __restrict__ alpha_p,
    const float* __restrict__ rmsw_ffn, bf16* __restrict__ a_bf)
{
    __shared__ float raw[16][512];
    __shared__ float red[4][16];
    __shared__ float rstdL[16];
    const int b = blockIdx.x, gi = blockIdx.y, ph = blockIdx.z;
    const int base = b*NS + (STR == 1 ? gi*16 : gi);
    const int tid = threadIdx.x, lane = tid & 63, wid = tid >> 6;
    #pragma unroll
    for (int e = 0; e < 8; ++e) {
        int idx = e*256 + tid;
        int k = idx >> 7, c4 = idx & 127;
        *(float4*)&raw[k][c4*4] = *(const float4*)&h[(size_t)(base + k*STR)*NH + c4*4];
    }
    __syncthreads();
    const int c0 = tid*2;
    float u0[16], u1[16], part[16];
    #pragma unroll
    for (int k = 0; k < 16; ++k) {
        float A = raw[k][c0], B = raw[k][c0+1];
        u0[k] = A; u1[k] = B; part[k] = A*A + B*B;
    }
    #pragma unroll
    for (int m = 1; m < 64; m <<= 1)
        #pragma unroll
        for (int k = 0; k < 16; ++k) part[k] += __shfl_xor(part[k], m, 64);
    if (lane == 0) {
        #pragma unroll
        for (int k = 0; k < 16; ++k) red[wid][k] = part[k];
    }
    __syncthreads();
    if (tid < 16)
        rstdL[tid] = rsqrtf((red[0][tid]+red[1][tid]+red[2][tid]+red[3][tid])*(1.f/NH) + EPSF);
    __syncthreads();
    #pragma unroll
    for (int k = 0; k < 16; ++k) { u0[k] *= rstdL[k]; u1[k] *= rstdL[k]; }
    const float al = *alpha_p;
    const float rc0 = rmsw[c0]*al, rc1 = rmsw[c0+1]*al;
    const uint32_t* wrow = (const uint32_t*)wT + tid;   // dword = channels (2t,2t+1)
    float hn0[8], hn1[8];
    #pragma unroll
    for (int pp = 0; pp < 8; ++pp) {
        const int p = ph*8 + pp;
        float a0 = 0.f, a1 = 0.f;
        #pragma unroll
        for (int k = 0; k < 16; ++k) {
            uint32_t wz = wrow[(p*16 + k)*256];
            float w0 = __builtin_bit_cast(float, wz << 16);
            float w1 = __builtin_bit_cast(float, wz & 0xffff0000u);
            a0 += w0*u0[k]; a1 += w1*u1[k];
        }
        hn0[pp] = raw[p][c0]   + rc0*a0;
        hn1[pp] = raw[p][c0+1] + rc1*a1;
        float2 o; o.x = hn0[pp]; o.y = hn1[pp];
        *(float2*)&h[(size_t)(base + p*STR)*NH + c0] = o;
    }
    if constexpr (FFN) {
        float p2[8];
        #pragma unroll
        for (int pp = 0; pp < 8; ++pp) p2[pp] = hn0[pp]*hn0[pp] + hn1[pp]*hn1[pp];
        #pragma unroll
        for (int m = 1; m < 64; m <<= 1)
            #pragma unroll
            for (int pp = 0; pp < 8; ++pp) p2[pp] += __shfl_xor(p2[pp], m, 64);
        __syncthreads();
        if (lane == 0) {
            #pragma unroll
            for (int pp = 0; pp < 8; ++pp) red[wid][pp] = p2[pp];
        }
        __syncthreads();
        if (tid < 8)
            rstdL[tid] = rsqrtf((red[0][tid]+red[1][tid]+red[2][tid]+red[3][tid])*(1.f/NH) + EPSF);
        __syncthreads();
        const float rf0 = rmsw_ffn[c0], rf1 = rmsw_ffn[c0+1];
        #pragma unroll
        for (int pp = 0; pp < 8; ++pp) {
            const int p = ph*8 + pp;
            float r = rstdL[pp];
            uint32_t pk = ((uint32_t)bfbits(hn1[pp]*r*rf1) << 16) | bfbits(hn0[pp]*r*rf0);
            *(uint32_t*)&a_bf[(size_t)(base + p*STR)*NH + c0] = pk;
        }
    }
}

// ---------------- head norm: a[t,c] = bf16(h[t,c]*rstd(t)*rmsw[c])
__global__ __launch_bounds__(256) void k_norm2(
    const float* __restrict__ h, const float* __restrict__ rmsw,
    bf16* __restrict__ a)
{
    const int t = blockIdx.x*4 + (threadIdx.x >> 6);
    const int lane = threadIdx.x & 63;
    const int c8 = lane*8;
    const float* src = &h[(size_t)t*NH + c8];
    float4 h0 = *(const float4*)&src[0];
    float4 h1 = *(const float4*)&src[4];
    float ss = h0.x*h0.x + h0.y*h0.y + h0.z*h0.z + h0.w*h0.w
             + h1.x*h1.x + h1.y*h1.y + h1.z*h1.z + h1.w*h1.w;
    #pragma unroll
    for (int m = 1; m < 64; m <<= 1) ss += __shfl_xor(ss, m, 64);
    const float rstd = rsqrtf(ss*(1.f/NH) + EPSF);
    float4 w0 = *(const float4*)&rmsw[c8];
    float4 w1 = *(const float4*)&rmsw[c8 + 4];
    bf16x8 o;
    o[0] = f2bf(h0.x*rstd*w0.x); o[1] = f2bf(h0.y*rstd*w0.y);
    o[2] = f2bf(h0.z*rstd*w0.z); o[3] = f2bf(h0.w*rstd*w0.w);
    o[4] = f2bf(h1.x*rstd*w1.x); o[5] = f2bf(h1.y*rstd*w1.y);
    o[6] = f2bf(h1.z*rstd*w1.z); o[7] = f2bf(h1.w*rstd*w1.w);
    *(bf16x8*)&a[(size_t)t*NH + c8] = o;
}

// ---------------- mlp in (BM=128): g = silu(wv . a) * (wg . a)   (bf16 out)
// grid (16,16); 4 waves 2Mx2N; wave tile 64x32 per GEMM; LDS 64KB, Gs aliased
__global__ __launch_bounds__(256) void k_mlp_in(
    const bf16* __restrict__ a, const bf16* __restrict__ wvl,
    const bf16* __restrict__ wgl, bf16* __restrict__ g)
{
    __shared__ __align__(16) char sm[65536];
    bf16* As  = (bf16*)sm;              // [2][8192] = 32KB (128 rows x 64 K, dbuf)
    bf16* B1s = (bf16*)(sm + 32768);    // [2][4096] = 16KB
    bf16* B3s = (bf16*)(sm + 49152);    // [2][4096] = 16KB
    bf16* Gs  = (bf16*)sm;              // epilogue alias: 128*72*2 = 18KB
    const int t0 = blockIdx.x*128, n0 = blockIdx.y*64;
    const int tid = threadIdx.x, lane = tid & 63, wv_ = tid >> 6;
    const int wm = wv_ >> 1, wn = wv_ & 1;
    const int fr = lane & 15, kq = lane >> 4;
    const bf16* Ag = a   + (size_t)t0*NH;
    const bf16* Vg = wvl + (size_t)n0*NH;
    const bf16* Gg = wgl + (size_t)n0*NH;
    f32x4 acc1[4][2] = {}, acc3[4][2] = {};
    stage64(Ag, NH, As, wv_, lane);
    stage64(Ag + (size_t)64*NH, NH, As + 4096, wv_, lane);
    stage64(Vg, NH, B1s, wv_, lane);
    stage64(Gg, NH, B3s, wv_, lane);
    __syncthreads();
    const int NIT = NH/64;   // 8
    for (int it = 0; it < NIT; ++it) {
        const int cur = it & 1;
        if (it + 1 < NIT) {
            const bf16* Ak = Ag + (it+1)*64;
            stage64(Ak, NH, As + (cur^1)*8192, wv_, lane);
            stage64(Ak + (size_t)64*NH, NH, As + (cur^1)*8192 + 4096, wv_, lane);
            stage64(Vg + (it+1)*64, NH, B1s + (cur^1)*4096, wv_, lane);
            stage64(Gg + (it+1)*64, NH, B3s + (cur^1)*4096, wv_, lane);
        }
        #pragma unroll
        for (int kk = 0; kk < 2; ++kk) {
            const int ch = kk*4 + kq;
            bf16x8 am[4];
            #pragma unroll
            for (int mi = 0; mi < 4; ++mi)
                am[mi] = *fragp(As + cur*8192, wm*64 + mi*16 + fr, ch);
            bf16x8 u0 = *fragp(B1s + cur*4096, wn*32 + fr,      ch);
            bf16x8 u1 = *fragp(B1s + cur*4096, wn*32 + 16 + fr, ch);
            bf16x8 v0 = *fragp(B3s + cur*4096, wn*32 + fr,      ch);
            bf16x8 v1 = *fragp(B3s + cur*4096, wn*32 + 16 + fr, ch);
            #pragma unroll
            for (int mi = 0; mi < 4; ++mi) {
                acc1[mi][0] = MFMA(am[mi], u0, acc1[mi][0]);
                acc1[mi][1] = MFMA(am[mi], u1, acc1[mi][1]);
                acc3[mi][0] = MFMA(am[mi], v0, acc3[mi][0]);
                acc3[mi][1] = MFMA(am[mi], v1, acc3[mi][1]);
            }
        }
        __syncthreads();
    }
    const int row4 = (lane >> 4)*4, col = lane & 15;
    #pragma unroll
    for (int mi = 0; mi < 4; ++mi)
      #pragma unroll
      for (int ni = 0; ni < 2; ++ni)
        #pragma unroll
        for (int r = 0; r < 4; ++r) {
            float xv = acc1[mi][ni][r];
            float gl = (xv / (1.f + __expf(-xv))) * acc3[mi][ni][r];
            Gs[(wm*64 + mi*16 + row4 + r)*72 + wn*32 + ni*16 + col] = f2bf(gl);
        }
    __syncthreads();
    const int rr = tid >> 1, c32 = (tid & 1)*32;
    #pragma unroll
    for (int j = 0; j < 4; ++j)
        *(bf16x8*)&g[(size_t)(t0 + rr)*NG + n0 + c32 + j*8] =
            *(const bf16x8*)&Gs[rr*72 + c32 + j*8];
}

// ---------------- mlp out (BM=128): h += alpha * (wo . g)
// grid (16,8); LDS 48KB, Cs aliased
__global__ __launch_bounds__(256) void k_mlp_out(
    const bf16* __restrict__ g, const bf16* __restrict__ wol,
    const float* __restrict__ alpha_p, float* __restrict__ h)
{
    __shared__ __align__(16) char sm[49152];
    bf16* As = (bf16*)sm;             // [2][8192] = 32KB
    bf16* Bs = (bf16*)(sm + 32768);   // [2][4096] = 16KB
    float* Cs = (float*)sm;           // epilogue alias: 128*66*4 = 33.8KB
    const int t0 = blockIdx.x*128, n0 = blockIdx.y*64;
    const int tid = threadIdx.x, lane = tid & 63, wv_ = tid >> 6;
    const int wm = wv_ >> 1, wn = wv_ & 1;
    const int fr = lane & 15, kq = lane >> 4;
    const bf16* Ag = g   + (size_t)t0*NG;
    const bf16* Bg = wol + (size_t)n0*NG;
    f32x4 acc[4][2] = {};
    stage64(Ag, NG, As, wv_, lane);
    stage64(Ag + (size_t)64*NG, NG, As + 4096, wv_, lane);
    stage64(Bg, NG, Bs, wv_, lane);
    __syncthreads();
    const int NIT = NG/64;   // 16
    for (int it = 0; it < NIT; ++it) {
        const int cur = it & 1;
        if (it + 1 < NIT) {
            const bf16* Ak = Ag + (it+1)*64;
            stage64(Ak, NG, As + (cur^1)*8192, wv_, lane);
            stage64(Ak + (size_t)64*NG, NG, As + (cur^1)*8192 + 4096, wv_, lane);
            stage64(Bg + (it+1)*64, NG, Bs + (cur^1)*4096, wv_, lane);
        }
        #pragma unroll
        for (int kk = 0; kk < 2; ++kk) {
            const int ch = kk*4 + kq;
            bf16x8 am[4];
            #pragma unroll
            for (int mi = 0; mi < 4; ++mi)
                am[mi] = *fragp(As + cur*8192, wm*64 + mi*16 + fr, ch);
            bf16x8 b0 = *fragp(Bs + cur*4096, wn*32 + fr,      ch);
            bf16x8 b1 = *fragp(Bs + cur*4096, wn*32 + 16 + fr, ch);
            #pragma unroll
            for (int mi = 0; mi < 4; ++mi) {
                acc[mi][0] = MFMA(am[mi], b0, acc[mi][0]);
                acc[mi][1] = MFMA(am[mi], b1, acc[mi][1]);
            }
        }
        __syncthreads();
    }
    const int row4 = (lane >> 4)*4, col = lane & 15;
    #pragma unroll
    for (int mi = 0; mi < 4; ++mi)
      #pragma unroll
      for (int ni = 0; ni < 2; ++ni)
        #pragma unroll
        for (int r = 0; r < 4; ++r)
            Cs[(wm*64 + mi*16 + row4 + r)*66 + wn*32 + ni*16 + col] = acc[mi][ni][r];
    __syncthreads();
    const float am_ = *alpha_p;
    const int rr = tid >> 1, c32 = (tid & 1)*32;
    float* dst = &h[(size_t)(t0 + rr)*NH + n0 + c32];
    #pragma unroll
    for (int j = 0; j < 8; ++j) {
        float4 hv = *(const float4*)&dst[j*4];
        float4 cv = *(const float4*)&Cs[rr*66 + c32 + j*4];
        hv.x += am_*cv.x; hv.y += am_*cv.y; hv.z += am_*cv.z; hv.w += am_*cv.w;
        *(float4*)&dst[j*4] = hv;
    }
}

// ---------------- head: logits = scale * head_w . a
__global__ __launch_bounds__(256) void k_head(
    const bf16* __restrict__ a, const bf16* __restrict__ hw,
    const float* __restrict__ scale_p, float* __restrict__ out)
{
    __shared__ __align__(16) bf16 As[2][4096], Bs[2][4096];
    __shared__ float Ls[64*66];
    const int t0 = blockIdx.x*64, n0 = blockIdx.y*64;
    const int tid = threadIdx.x, lane = tid & 63, wv_ = tid >> 6;
    const int wm = wv_ >> 1, wn = wv_ & 1;
    const int fr = lane & 15, kq = lane >> 4;
    const bf16* Ag = a  + (size_t)t0*NH;
    const bf16* Bg = hw + (size_t)n0*NH;
    f32x4 acc[2][2] = {};
    stage64(Ag, NH, As[0], wv_, lane);
    stage64(Bg, NH, Bs[0], wv_, lane);
    __syncthreads();
    const int NIT = NH/64;
    for (int it = 0; it < NIT; ++it) {
        const int cur = it & 1;
        if (it + 1 < NIT) {
            stage64(Ag + (it+1)*64, NH, As[cur^1], wv_, lane);
            stage64(Bg + (it+1)*64, NH, Bs[cur^1], wv_, lane);
        }
        #pragma unroll
        for (int kk = 0; kk < 2; ++kk) {
            const int ch = kk*4 + kq;
            bf16x8 a0 = *fragp(As[cur], wm*32 + fr,      ch);
            bf16x8 a1 = *fragp(As[cur], wm*32 + 16 + fr, ch);
            bf16x8 b0 = *fragp(Bs[cur], wn*32 + fr,      ch);
            bf16x8 b1 = *fragp(Bs[cur], wn*32 + 16 + fr, ch);
            acc[0][0] = MFMA(a0, b0, acc[0][0]);
            acc[0][1] = MFMA(a0, b1, acc[0][1]);
            acc[1][0] = MFMA(a1, b0, acc[1][0]);
            acc[1][1] = MFMA(a1, b1, acc[1][1]);
        }
        __syncthreads();
    }
    const float sc = *scale_p;
    const int row4 = (lane >> 4)*4, col = lane & 15;
    #pragma unroll
    for (int mi = 0; mi < 2; ++mi)
      #pragma unroll
      for (int ni = 0; ni < 2; ++ni)
        #pragma unroll
        for (int r = 0; r < 4; ++r)
            Ls[(wm*32 + mi*16 + row4 + r)*66 + wn*32 + ni*16 + col] = sc * acc[mi][ni][r];
    __syncthreads();
    const int vv = tid >> 2, s16 = (tid & 3)*16;
    const int b = t0 >> 8, s0 = t0 & 255;
    float* dst = &out[((size_t)(b*NV + n0 + vv))*NS + s0 + s16];
    #pragma unroll
    for (int i = 0; i < 16; ++i) dst[i] = Ls[(s16 + i)*66 + vv];
}

extern "C" void kernel_launch(void* const* d_in, const int* in_sizes, int n_in,
                              void* d_out, int out_size, void* d_ws, size_t ws_size,
                              hipStream_t stream) {
    const float* x          = (const float*)d_in[0];
    const float* stem_w     = (const float*)d_in[1];
    const float* rms_local  = (const float*)d_in[2];
    const float* rms_global = (const float*)d_in[3];
    const float* rms_ffn    = (const float*)d_in[4];
    const float* alpha_local  = (const float*)d_in[5];
    const float* alpha_global = (const float*)d_in[6];
    const float* alpha_mlp    = (const float*)d_in[7];
    const float* w_local    = (const float*)d_in[8];
    const float* w_global   = (const float*)d_in[9];
    const float* wv         = (const float*)d_in[10];
    const float* wg         = (const float*)d_in[11];
    const float* wo         = (const float*)d_in[12];
    const float* head_rms   = (const float*)d_in[13];
    const float* head_scale = (const float*)d_in[14];
    const float* head_w     = (const float*)d_in[15];
    float* out = (float*)d_out;

    char* ws = (char*)d_ws;
    const size_t MB = 1024*1024;
    float* h    = (float*)(ws);                 // 4MB
    bf16*  g    = (bf16*)(ws + 4*MB);           // 4MB
    bf16*  a_bf = (bf16*)(ws + 8*MB);           // 2MB
    bf16* xT      = (bf16*)(ws + 16*MB);        // 1.31MB
    bf16* stem_wb = (bf16*)(ws + 18*MB);        // 0.33MB
    bf16* head_wb = (bf16*)(ws + 19*MB);        // 0.26MB
    bf16* wlT     = (bf16*)(ws + 20*MB);        // 6MB
    bf16* wgT     = (bf16*)(ws + 26*MB);        // 6MB
    bf16* wv_b    = (bf16*)(ws + 32*MB);        // 24MB
    bf16* wg_b    = (bf16*)(ws + 56*MB);        // 24MB
    bf16* wo_b    = (bf16*)(ws + 80*MB);        // 24MB -> end 104MB

    // init: 3 dispatches
    k_cvt_all<<<4096, 256, 0, stream>>>(wv, wg, wo, stem_w, head_w,
                                        wv_b, wg_b, wo_b, stem_wb, head_wb);
    k_trw<<<dim3(4, 8, 48), 256, 0, stream>>>(w_local, w_global, wlT, wgT);
    k_trx<<<dim3(4, 5, 8), 256, 0, stream>>>(x, xT);

    k_stem_b<<<dim3(32, 8), 256, 0, stream>>>(xT, stem_wb, h);

    for (int l = 0; l < NL; ++l) {
        k_mix2<1, false><<<dim3(NB, 16, 2), 256, 0, stream>>>(
            h, wlT + (size_t)l*256*NH, rms_local + l*NH, alpha_local + l,
            nullptr, nullptr);
        k_mix2<16, true><<<dim3(NB, 16, 2), 256, 0, stream>>>(
            h, wgT + (size_t)l*256*NH, rms_global + l*NH, alpha_global + l,
            rms_ffn + l*NH, a_bf);
        k_mlp_in<<<dim3(16, 16), 256, 0, stream>>>(
            a_bf, wv_b + (size_t)l*NG*NH, wg_b + (size_t)l*NG*NH, g);
        k_mlp_out<<<dim3(16, 8), 256, 0, stream>>>(
            g, wo_b + (size_t)l*NH*NG, alpha_mlp + l, h);
    }
    k_norm2<<<512, 256, 0, stream>>>(h, head_rms, a_bf);
    k_head<<<dim3(32, 4), 256, 0, stream>>>(a_bf, head_wb, head_scale, out);
}

// Round 20
// 1132.448 us; speedup vs baseline: 1.0530x; 1.0002x over previous
//
#include <hip/hip_runtime.h>
#include <hip/hip_bf16.h>
#include <stdint.h>

#define NB 8
#define NS 256
#define NH 512
#define NG 1024
#define NV 256
#define NL 24
#define NC 320
#define NT 2048
#define EPSF 1e-5f

typedef __bf16 bf16;
typedef bf16 bf16x8 __attribute__((ext_vector_type(8)));
typedef float f32x4 __attribute__((ext_vector_type(4)));

__device__ __forceinline__ bf16 f2bf(float f) {
    uint32_t u = __builtin_bit_cast(uint32_t, f);
    u += 0x7FFFu + ((u >> 16) & 1u);
    uint16_t b = (uint16_t)(u >> 16);
    return __builtin_bit_cast(bf16, b);
}
__device__ __forceinline__ uint16_t bfbits(float f) {
    uint32_t u = __builtin_bit_cast(uint32_t, f);
    u += 0x7FFFu + ((u >> 16) & 1u);
    return (uint16_t)(u >> 16);
}

__device__ __forceinline__ void gload16(const void* g, void* l) {
    __builtin_amdgcn_global_load_lds(
        (const __attribute__((address_space(1))) void*)g,
        (__attribute__((address_space(3))) void*)l,
        16, 0, 0);
}

// stage 64-row x 64-elem bf16 tile; LDS chunk XOR-swizzled via pre-swizzled src
__device__ __forceinline__ void stage64(
    const bf16* __restrict__ src, int ldk, bf16* lds, int wv_, int lane)
{
    #pragma unroll
    for (int j = 0; j < 2; ++j) {
        const int gI = wv_*2 + j;
        const int r  = gI*8 + (lane >> 3);
        const int ch = (lane & 7) ^ (lane >> 3);
        gload16(src + (size_t)r*ldk + ch*8, lds + gI*512);
    }
}
__device__ __forceinline__ const bf16x8* fragp(const bf16* lds, int row, int ch) {
    return (const bf16x8*)(lds + row*64 + ((ch ^ (row & 7)) << 3));
}

#define MFMA(a,b,c) __builtin_amdgcn_mfma_f32_16x16x32_bf16(a, b, c, 0, 0, 0)

// ---------------- init: convert ALL weights, 4-deep ILP grid-stride
__device__ __forceinline__ void cvt_one(
    int i, int n1, int n4,
    const float* __restrict__ wv, const float* __restrict__ wg,
    const float* __restrict__ wo, const float* __restrict__ sw,
    const float* __restrict__ hw, bf16* __restrict__ dwv,
    bf16* __restrict__ dwg, bf16* __restrict__ dwo,
    bf16* __restrict__ dsw, bf16* __restrict__ dhw)
{
    const float* s; bf16* d; int j;
    if (i < n1)            { s = wv; d = dwv; j = i; }
    else if (i < 2*n1)     { s = wg; d = dwg; j = i - n1; }
    else if (i < 3*n1)     { s = wo; d = dwo; j = i - 2*n1; }
    else if (i < 3*n1+n4)  { s = sw; d = dsw; j = i - 3*n1; }
    else                   { s = hw; d = dhw; j = i - 3*n1 - n4; }
    const float* sp = s + (size_t)j*8;
    float4 v0 = *(const float4*)&sp[0];
    float4 v1 = *(const float4*)&sp[4];
    bf16x8 t;
    t[0] = f2bf(v0.x); t[1] = f2bf(v0.y); t[2] = f2bf(v0.z); t[3] = f2bf(v0.w);
    t[4] = f2bf(v1.x); t[5] = f2bf(v1.y); t[6] = f2bf(v1.z); t[7] = f2bf(v1.w);
    *(bf16x8*)&d[(size_t)j*8] = t;
}

__global__ __launch_bounds__(256) void k_cvt_all(
    const float* __restrict__ wv, const float* __restrict__ wg,
    const float* __restrict__ wo, const float* __restrict__ sw,
    const float* __restrict__ hw, bf16* __restrict__ dwv,
    bf16* __restrict__ dwg, bf16* __restrict__ dwo,
    bf16* __restrict__ dsw, bf16* __restrict__ dhw)
{
    const int n1 = NL*NG*NH/8;          // 1572864
    const int n4 = NH*NC/8;             // 20480
    const int n5 = NV*NH/8;             // 16384
    const int N = 3*n1 + n4 + n5;
    const int stride = gridDim.x*256;
    int i = blockIdx.x*256 + threadIdx.x;
    for (; i + 3*stride < N; i += 4*stride) {
        cvt_one(i,            n1, n4, wv, wg, wo, sw, hw, dwv, dwg, dwo, dsw, dhw);
        cvt_one(i +   stride, n1, n4, wv, wg, wo, sw, hw, dwv, dwg, dwo, dsw, dhw);
        cvt_one(i + 2*stride, n1, n4, wv, wg, wo, sw, hw, dwv, dwg, dwo, dsw, dhw);
        cvt_one(i + 3*stride, n1, n4, wv, wg, wo, sw, hw, dwv, dwg, dwo, dsw, dhw);
    }
    for (; i < N; i += stride)
        cvt_one(i, n1, n4, wv, wg, wo, sw, hw, dwv, dwg, dwo, dsw, dhw);
}

// ---------------- init: transpose mix weights [l][c][pj] f32 -> [l][pj][c] bf16
__global__ __launch_bounds__(256) void k_trw(
    const float* __restrict__ wl, const float* __restrict__ wg,
    bf16* __restrict__ wlT, bf16* __restrict__ wgT)
{
    __shared__ bf16 Ls[64*72];
    const int pj0 = blockIdx.x*64, c0 = blockIdx.y*64;
    const int z = blockIdx.z, l = z >> 1;
    const float* src = (z & 1) ? wg : wl;
    bf16* dst = (z & 1) ? wgT : wlT;
    src += (size_t)l*NH*256;
    dst += (size_t)l*256*NH;
    const int tid = threadIdx.x;
    #pragma unroll
    for (int e = 0; e < 16; ++e) {
        int idx = e*256 + tid;
        int cl = idx >> 6, pj = idx & 63;
        Ls[pj*72 + cl] = f2bf(src[(size_t)(c0 + cl)*256 + pj0 + pj]);
    }
    __syncthreads();
    #pragma unroll
    for (int e = 0; e < 2; ++e) {
        int idx = e*256 + tid;
        int row = idx >> 3, ch8 = idx & 7;
        *(bf16x8*)&dst[(size_t)(pj0 + row)*NH + c0 + ch8*8] =
            *(const bf16x8*)&Ls[row*72 + ch8*8];
    }
}

// ---------------- init: x[b][c][s] f32 -> xT[b*256+s][c] bf16
__global__ __launch_bounds__(256) void k_trx(
    const float* __restrict__ x, bf16* __restrict__ xT)
{
    __shared__ bf16 Ls[64*72];
    const int s0 = blockIdx.x*64, c0 = blockIdx.y*64, b = blockIdx.z;
    const int tid = threadIdx.x;
    #pragma unroll
    for (int e = 0; e < 16; ++e) {
        int idx = tid + e*256;
        int c = idx >> 6, s = idx & 63;
        Ls[s*72 + c] = f2bf(x[(size_t)(b*NC + c0 + c)*NS + s0 + s]);
    }
    __syncthreads();
    #pragma unroll
    for (int e = 0; e < 2; ++e) {
        int idx = tid + e*256;
        int s = idx >> 3, ch = idx & 7;
        *(bf16x8*)&xT[(size_t)(b*NS + s0 + s)*NC + c0 + ch*8] =
            *(const bf16x8*)&Ls[s*72 + ch*8];
    }
}

// ---------------- stem GEMM: h[t,o] = xT[t,:] . wb[o,:]
__global__ __launch_bounds__(256) void k_stem_b(
    const bf16* __restrict__ xT, const bf16* __restrict__ wb,
    float* __restrict__ h)
{
    __shared__ __align__(16) bf16 As[2][4096], Bs[2][4096];
    __shared__ float Cs[64*66];
    const int t0 = blockIdx.x*64, n0 = blockIdx.y*64;
    const int tid = threadIdx.x, lane = tid & 63, wv_ = tid >> 6;
    const int wm = wv_ >> 1, wn = wv_ & 1;
    const int fr = lane & 15, kq = lane >> 4;
    const bf16* Ag = xT + (size_t)t0*NC;
    const bf16* Bg = wb + (size_t)n0*NC;
    f32x4 acc[2][2] = {};
    stage64(Ag, NC, As[0], wv_, lane);
    stage64(Bg, NC, Bs[0], wv_, lane);
    __syncthreads();
    const int NIT = NC/64;
    for (int it = 0; it < NIT; ++it) {
        const int cur = it & 1;
        if (it + 1 < NIT) {
            stage64(Ag + (it+1)*64, NC, As[cur^1], wv_, lane);
            stage64(Bg + (it+1)*64, NC, Bs[cur^1], wv_, lane);
        }
        #pragma unroll
        for (int kk = 0; kk < 2; ++kk) {
            const int ch = kk*4 + kq;
            bf16x8 a0 = *fragp(As[cur], wm*32 + fr,      ch);
            bf16x8 a1 = *fragp(As[cur], wm*32 + 16 + fr, ch);
            bf16x8 b0 = *fragp(Bs[cur], wn*32 + fr,      ch);
            bf16x8 b1 = *fragp(Bs[cur], wn*32 + 16 + fr, ch);
            acc[0][0] = MFMA(a0, b0, acc[0][0]);
            acc[0][1] = MFMA(a0, b1, acc[0][1]);
            acc[1][0] = MFMA(a1, b0, acc[1][0]);
            acc[1][1] = MFMA(a1, b1, acc[1][1]);
        }
        __syncthreads();
    }
    const int row4 = (lane >> 4)*4, col = lane & 15;
    #pragma unroll
    for (int mi = 0; mi < 2; ++mi)
      #pragma unroll
      for (int ni = 0; ni < 2; ++ni)
        #pragma unroll
        for (int r = 0; r < 4; ++r)
            Cs[(wm*32 + mi*16 + row4 + r)*66 + wn*32 + ni*16 + col] = acc[mi][ni][r];
    __syncthreads();
    const int rr = tid >> 2, c16 = (tid & 3)*16;
    float* dst = &h[(size_t)(t0 + rr)*NH + n0 + c16];
    #pragma unroll
    for (int i = 0; i < 16; ++i) dst[i] = Cs[rr*66 + c16 + i];
}

// ---------------- unified mix with block-local RMS norm, split output-tokens
template<int STR, bool FFN>
__global__ __launch_bounds__(256) void k_mix2(
    float* __restrict__ h, const bf16* __restrict__ wT,
    const float* __restrict__ rmsw, const float* __restrict__ alpha_p,
    const float* __restrict__ rmsw_ffn, bf16* __restrict__ a_bf)
{
    __shared__ float raw[16][512];
    __shared__ float red[4][16];
    __shared__ float rstdL[16];
    const int b = blockIdx.x, gi = blockIdx.y, ph = blockIdx.z;
    const int base = b*NS + (STR == 1 ? gi*16 : gi);
    const int tid = threadIdx.x, lane = tid & 63, wid = tid >> 6;
    #pragma unroll
    for (int e = 0; e < 8; ++e) {
        int idx = e*256 + tid;
        int k = idx >> 7, c4 = idx & 127;
        *(float4*)&raw[k][c4*4] = *(const float4*)&h[(size_t)(base + k*STR)*NH + c4*4];
    }
    __syncthreads();
    const int c0 = tid*2;
    float u0[16], u1[16], part[16];
    #pragma unroll
    for (int k = 0; k < 16; ++k) {
        float A = raw[k][c0], B = raw[k][c0+1];
        u0[k] = A; u1[k] = B; part[k] = A*A + B*B;
    }
    #pragma unroll
    for (int m = 1; m < 64; m <<= 1)
        #pragma unroll
        for (int k = 0; k < 16; ++k) part[k] += __shfl_xor(part[k], m, 64);
    if (lane == 0) {
        #pragma unroll
        for (int k = 0; k < 16; ++k) red[wid][k] = part[k];
    }
    __syncthreads();
    if (tid < 16)
        rstdL[tid] = rsqrtf((red[0][tid]+red[1][tid]+red[2][tid]+red[3][tid])*(1.f/NH) + EPSF);
    __syncthreads();
    #pragma unroll
    for (int k = 0; k < 16; ++k) { u0[k] *= rstdL[k]; u1[k] *= rstdL[k]; }
    const float al = *alpha_p;
    const float rc0 = rmsw[c0]*al, rc1 = rmsw[c0+1]*al;
    const uint32_t* wrow = (const uint32_t*)wT + tid;   // dword = channels (2t,2t+1)
    float hn0[8], hn1[8];
    #pragma unroll
    for (int pp = 0; pp < 8; ++pp) {
        const int p = ph*8 + pp;
        float a0 = 0.f, a1 = 0.f;
        #pragma unroll
        for (int k = 0; k < 16; ++k) {
            uint32_t wz = wrow[(p*16 + k)*256];
            float w0 = __builtin_bit_cast(float, wz << 16);
            float w1 = __builtin_bit_cast(float, wz & 0xffff0000u);
            a0 += w0*u0[k]; a1 += w1*u1[k];
        }
        hn0[pp] = raw[p][c0]   + rc0*a0;
        hn1[pp] = raw[p][c0+1] + rc1*a1;
        float2 o; o.x = hn0[pp]; o.y = hn1[pp];
        *(float2*)&h[(size_t)(base + p*STR)*NH + c0] = o;
    }
    if constexpr (FFN) {
        float p2[8];
        #pragma unroll
        for (int pp = 0; pp < 8; ++pp) p2[pp] = hn0[pp]*hn0[pp] + hn1[pp]*hn1[pp];
        #pragma unroll
        for (int m = 1; m < 64; m <<= 1)
            #pragma unroll
            for (int pp = 0; pp < 8; ++pp) p2[pp] += __shfl_xor(p2[pp], m, 64);
        __syncthreads();
        if (lane == 0) {
            #pragma unroll
            for (int pp = 0; pp < 8; ++pp) red[wid][pp] = p2[pp];
        }
        __syncthreads();
        if (tid < 8)
            rstdL[tid] = rsqrtf((red[0][tid]+red[1][tid]+red[2][tid]+red[3][tid])*(1.f/NH) + EPSF);
        __syncthreads();
        const float rf0 = rmsw_ffn[c0], rf1 = rmsw_ffn[c0+1];
        #pragma unroll
        for (int pp = 0; pp < 8; ++pp) {
            const int p = ph*8 + pp;
            float r = rstdL[pp];
            uint32_t pk = ((uint32_t)bfbits(hn1[pp]*r*rf1) << 16) | bfbits(hn0[pp]*r*rf0);
            *(uint32_t*)&a_bf[(size_t)(base + p*STR)*NH + c0] = pk;
        }
    }
}

// ---------------- head norm: a[t,c] = bf16(h[t,c]*rstd(t)*rmsw[c])
__global__ __launch_bounds__(256) void k_norm2(
    const float* __restrict__ h, const float* __restrict__ rmsw,
    bf16* __restrict__ a)
{
    const int t = blockIdx.x*4 + (threadIdx.x >> 6);
    const int lane = threadIdx.x & 63;
    const int c8 = lane*8;
    const float* src = &h[(size_t)t*NH + c8];
    float4 h0 = *(const float4*)&src[0];
    float4 h1 = *(const float4*)&src[4];
    float ss = h0.x*h0.x + h0.y*h0.y + h0.z*h0.z + h0.w*h0.w
             + h1.x*h1.x + h1.y*h1.y + h1.z*h1.z + h1.w*h1.w;
    #pragma unroll
    for (int m = 1; m < 64; m <<= 1) ss += __shfl_xor(ss, m, 64);
    const float rstd = rsqrtf(ss*(1.f/NH) + EPSF);
    float4 w0 = *(const float4*)&rmsw[c8];
    float4 w1 = *(const float4*)&rmsw[c8 + 4];
    bf16x8 o;
    o[0] = f2bf(h0.x*rstd*w0.x); o[1] = f2bf(h0.y*rstd*w0.y);
    o[2] = f2bf(h0.z*rstd*w0.z); o[3] = f2bf(h0.w*rstd*w0.w);
    o[4] = f2bf(h1.x*rstd*w1.x); o[5] = f2bf(h1.y*rstd*w1.y);
    o[6] = f2bf(h1.z*rstd*w1.z); o[7] = f2bf(h1.w*rstd*w1.w);
    *(bf16x8*)&a[(size_t)t*NH + c8] = o;
}

// ---------------- mlp in (BM=128): g = silu(wv . a) * (wg . a)   (bf16 out)
// grid (16,16); 4 waves 2Mx2N; wave tile 64x32 per GEMM; LDS 64KB, Gs aliased
__global__ __launch_bounds__(256) void k_mlp_in(
    const bf16* __restrict__ a, const bf16* __restrict__ wvl,
    const bf16* __restrict__ wgl, bf16* __restrict__ g)
{
    __shared__ __align__(16) char sm[65536];
    bf16* As  = (bf16*)sm;              // [2][8192] = 32KB (128 rows x 64 K, dbuf)
    bf16* B1s = (bf16*)(sm + 32768);    // [2][4096] = 16KB
    bf16* B3s = (bf16*)(sm + 49152);    // [2][4096] = 16KB
    bf16* Gs  = (bf16*)sm;              // epilogue alias: 128*72*2 = 18KB
    const int t0 = blockIdx.x*128, n0 = blockIdx.y*64;
    const int tid = threadIdx.x, lane = tid & 63, wv_ = tid >> 6;
    const int wm = wv_ >> 1, wn = wv_ & 1;
    const int fr = lane & 15, kq = lane >> 4;
    const bf16* Ag = a   + (size_t)t0*NH;
    const bf16* Vg = wvl + (size_t)n0*NH;
    const bf16* Gg = wgl + (size_t)n0*NH;
    f32x4 acc1[4][2] = {}, acc3[4][2] = {};
    stage64(Ag, NH, As, wv_, lane);
    stage64(Ag + (size_t)64*NH, NH, As + 4096, wv_, lane);
    stage64(Vg, NH, B1s, wv_, lane);
    stage64(Gg, NH, B3s, wv_, lane);
    __syncthreads();
    const int NIT = NH/64;   // 8
    for (int it = 0; it < NIT; ++it) {
        const int cur = it & 1;
        if (it + 1 < NIT) {
            const bf16* Ak = Ag + (it+1)*64;
            stage64(Ak, NH, As + (cur^1)*8192, wv_, lane);
            stage64(Ak + (size_t)64*NH, NH, As + (cur^1)*8192 + 4096, wv_, lane);
            stage64(Vg + (it+1)*64, NH, B1s + (cur^1)*4096, wv_, lane);
            stage64(Gg + (it+1)*64, NH, B3s + (cur^1)*4096, wv_, lane);
        }
        #pragma unroll
        for (int kk = 0; kk < 2; ++kk) {
            const int ch = kk*4 + kq;
            bf16x8 am[4];
            #pragma unroll
            for (int mi = 0; mi < 4; ++mi)
                am[mi] = *fragp(As + cur*8192, wm*64 + mi*16 + fr, ch);
            bf16x8 u0 = *fragp(B1s + cur*4096, wn*32 + fr,      ch);
            bf16x8 u1 = *fragp(B1s + cur*4096, wn*32 + 16 + fr, ch);
            bf16x8 v0 = *fragp(B3s + cur*4096, wn*32 + fr,      ch);
            bf16x8 v1 = *fragp(B3s + cur*4096, wn*32 + 16 + fr, ch);
            #pragma unroll
            for (int mi = 0; mi < 4; ++mi) {
                acc1[mi][0] = MFMA(am[mi], u0, acc1[mi][0]);
                acc1[mi][1] = MFMA(am[mi], u1, acc1[mi][1]);
                acc3[mi][0] = MFMA(am[mi], v0, acc3[mi][0]);
                acc3[mi][1] = MFMA(am[mi], v1, acc3[mi][1]);
            }
        }
        __syncthreads();
    }
    const int row4 = (lane >> 4)*4, col = lane & 15;
    #pragma unroll
    for (int mi = 0; mi < 4; ++mi)
      #pragma unroll
      for (int ni = 0; ni < 2; ++ni)
        #pragma unroll
        for (int r = 0; r < 4; ++r) {
            float xv = acc1[mi][ni][r];
            float gl = (xv / (1.f + __expf(-xv))) * acc3[mi][ni][r];
            Gs[(wm*64 + mi*16 + row4 + r)*72 + wn*32 + ni*16 + col] = f2bf(gl);
        }
    __syncthreads();
    const int rr = tid >> 1, c32 = (tid & 1)*32;
    #pragma unroll
    for (int j = 0; j < 4; ++j)
        *(bf16x8*)&g[(size_t)(t0 + rr)*NG + n0 + c32 + j*8] =
            *(const bf16x8*)&Gs[rr*72 + c32 + j*8];
}

// ---------------- mlp out (BM=128): h += alpha * (wo . g)
// grid (16,8); LDS 48KB, Cs aliased
__global__ __launch_bounds__(256) void k_mlp_out(
    const bf16* __restrict__ g, const bf16* __restrict__ wol,
    const float* __restrict__ alpha_p, float* __restrict__ h)
{
    __shared__ __align__(16) char sm[49152];
    bf16* As = (bf16*)sm;             // [2][8192] = 32KB
    bf16* Bs = (bf16*)(sm + 32768);   // [2][4096] = 16KB
    float* Cs = (float*)sm;           // epilogue alias: 128*66*4 = 33.8KB
    const int t0 = blockIdx.x*128, n0 = blockIdx.y*64;
    const int tid = threadIdx.x, lane = tid & 63, wv_ = tid >> 6;
    const int wm = wv_ >> 1, wn = wv_ & 1;
    const int fr = lane & 15, kq = lane >> 4;
    const bf16* Ag = g   + (size_t)t0*NG;
    const bf16* Bg = wol + (size_t)n0*NG;
    f32x4 acc[4][2] = {};
    stage64(Ag, NG, As, wv_, lane);
    stage64(Ag + (size_t)64*NG, NG, As + 4096, wv_, lane);
    stage64(Bg, NG, Bs, wv_, lane);
    __syncthreads();
    const int NIT = NG/64;   // 16
    for (int it = 0; it < NIT; ++it) {
        const int cur = it & 1;
        if (it + 1 < NIT) {
            const bf16* Ak = Ag + (it+1)*64;
            stage64(Ak, NG, As + (cur^1)*8192, wv_, lane);
            stage64(Ak + (size_t)64*NG, NG, As + (cur^1)*8192 + 4096, wv_, lane);
            stage64(Bg + (it+1)*64, NG, Bs + (cur^1)*4096, wv_, lane);
        }
        #pragma unroll
        for (int kk = 0; kk < 2; ++kk) {
            const int ch = kk*4 + kq;
            bf16x8 am[4];
            #pragma unroll
            for (int mi = 0; mi < 4; ++mi)
                am[mi] = *fragp(As + cur*8192, wm*64 + mi*16 + fr, ch);
            bf16x8 b0 = *fragp(Bs + cur*4096, wn*32 + fr,      ch);
            bf16x8 b1 = *fragp(Bs + cur*4096, wn*32 + 16 + fr, ch);
            #pragma unroll
            for (int mi = 0; mi < 4; ++mi) {
                acc[mi][0] = MFMA(am[mi], b0, acc[mi][0]);
                acc[mi][1] = MFMA(am[mi], b1, acc[mi][1]);
            }
        }
        __syncthreads();
    }
    const int row4 = (lane >> 4)*4, col = lane & 15;
    #pragma unroll
    for (int mi = 0; mi < 4; ++mi)
      #pragma unroll
      for (int ni = 0; ni < 2; ++ni)
        #pragma unroll
        for (int r = 0; r < 4; ++r)
            Cs[(wm*64 + mi*16 + row4 + r)*66 + wn*32 + ni*16 + col] = acc[mi][ni][r];
    __syncthreads();
    const float am_ = *alpha_p;
    const int rr = tid >> 1, c32 = (tid & 1)*32;
    float* dst = &h[(size_t)(t0 + rr)*NH + n0 + c32];
    #pragma unroll
    for (int j = 0; j < 8; ++j) {
        float4 hv = *(const float4*)&dst[j*4];
        float4 cv = *(const float4*)&Cs[rr*66 + c32 + j*4];
        hv.x += am_*cv.x; hv.y += am_*cv.y; hv.z += am_*cv.z; hv.w += am_*cv.w;
        *(float4*)&dst[j*4] = hv;
    }
}

// ---------------- head: logits = scale * head_w . a
__global__ __launch_bounds__(256) void k_head(
    const bf16* __restrict__ a, const bf16* __restrict__ hw,
    const float* __restrict__ scale_p, float* __restrict__ out)
{
    __shared__ __align__(16) bf16 As[2][4096], Bs[2][4096];
    __shared__ float Ls[64*66];
    const int t0 = blockIdx.x*64, n0 = blockIdx.y*64;
    const int tid = threadIdx.x, lane = tid & 63, wv_ = tid >> 6;
    const int wm = wv_ >> 1, wn = wv_ & 1;
    const int fr = lane & 15, kq = lane >> 4;
    const bf16* Ag = a  + (size_t)t0*NH;
    const bf16* Bg = hw + (size_t)n0*NH;
    f32x4 acc[2][2] = {};
    stage64(Ag, NH, As[0], wv_, lane);
    stage64(Bg, NH, Bs[0], wv_, lane);
    __syncthreads();
    const int NIT = NH/64;
    for (int it = 0; it < NIT; ++it) {
        const int cur = it & 1;
        if (it + 1 < NIT) {
            stage64(Ag + (it+1)*64, NH, As[cur^1], wv_, lane);
            stage64(Bg + (it+1)*64, NH, Bs[cur^1], wv_, lane);
        }
        #pragma unroll
        for (int kk = 0; kk < 2; ++kk) {
            const int ch = kk*4 + kq;
            bf16x8 a0 = *fragp(As[cur], wm*32 + fr,      ch);
            bf16x8 a1 = *fragp(As[cur], wm*32 + 16 + fr, ch);
            bf16x8 b0 = *fragp(Bs[cur], wn*32 + fr,      ch);
            bf16x8 b1 = *fragp(Bs[cur], wn*32 + 16 + fr, ch);
            acc[0][0] = MFMA(a0, b0, acc[0][0]);
            acc[0][1] = MFMA(a0, b1, acc[0][1]);
            acc[1][0] = MFMA(a1, b0, acc[1][0]);
            acc[1][1] = MFMA(a1, b1, acc[1][1]);
        }
        __syncthreads();
    }
    const float sc = *scale_p;
    const int row4 = (lane >> 4)*4, col = lane & 15;
    #pragma unroll
    for (int mi = 0; mi < 2; ++mi)
      #pragma unroll
      for (int ni = 0; ni < 2; ++ni)
        #pragma unroll
        for (int r = 0; r < 4; ++r)
            Ls[(wm*32 + mi*16 + row4 + r)*66 + wn*32 + ni*16 + col] = sc * acc[mi][ni][r];
    __syncthreads();
    const int vv = tid >> 2, s16 = (tid & 3)*16;
    const int b = t0 >> 8, s0 = t0 & 255;
    float* dst = &out[((size_t)(b*NV + n0 + vv))*NS + s0 + s16];
    #pragma unroll
    for (int i = 0; i < 16; ++i) dst[i] = Ls[(s16 + i)*66 + vv];
}

extern "C" void kernel_launch(void* const* d_in, const int* in_sizes, int n_in,
                              void* d_out, int out_size, void* d_ws, size_t ws_size,
                              hipStream_t stream) {
    const float* x          = (const float*)d_in[0];
    const float* stem_w     = (const float*)d_in[1];
    const float* rms_local  = (const float*)d_in[2];
    const float* rms_global = (const float*)d_in[3];
    const float* rms_ffn    = (const float*)d_in[4];
    const float* alpha_local  = (const float*)d_in[5];
    const float* alpha_global = (const float*)d_in[6];
    const float* alpha_mlp    = (const float*)d_in[7];
    const float* w_local    = (const float*)d_in[8];
    const float* w_global   = (const float*)d_in[9];
    const float* wv         = (const float*)d_in[10];
    const float* wg         = (const float*)d_in[11];
    const float* wo         = (const float*)d_in[12];
    const float* head_rms   = (const float*)d_in[13];
    const float* head_scale = (const float*)d_in[14];
    const float* head_w     = (const float*)d_in[15];
    float* out = (float*)d_out;

    char* ws = (char*)d_ws;
    const size_t MB = 1024*1024;
    float* h    = (float*)(ws);                 // 4MB
    bf16*  g    = (bf16*)(ws + 4*MB);           // 4MB
    bf16*  a_bf = (bf16*)(ws + 8*MB);           // 2MB
    bf16* xT      = (bf16*)(ws + 16*MB);        // 1.31MB
    bf16* stem_wb = (bf16*)(ws + 18*MB);        // 0.33MB
    bf16* head_wb = (bf16*)(ws + 19*MB);        // 0.26MB
    bf16* wlT     = (bf16*)(ws + 20*MB);        // 6MB
    bf16* wgT     = (bf16*)(ws + 26*MB);        // 6MB
    bf16* wv_b    = (bf16*)(ws + 32*MB);        // 24MB
    bf16* wg_b    = (bf16*)(ws + 56*MB);        // 24MB
    bf16* wo_b    = (bf16*)(ws + 80*MB);        // 24MB -> end 104MB

    // init: 3 dispatches
    k_cvt_all<<<1024, 256, 0, stream>>>(wv, wg, wo, stem_w, head_w,
                                        wv_b, wg_b, wo_b, stem_wb, head_wb);
    k_trw<<<dim3(4, 8, 48), 256, 0, stream>>>(w_local, w_global, wlT, wgT);
    k_trx<<<dim3(4, 5, 8), 256, 0, stream>>>(x, xT);

    k_stem_b<<<dim3(32, 8), 256, 0, stream>>>(xT, stem_wb, h);

    for (int l = 0; l < NL; ++l) {
        k_mix2<1, false><<<dim3(NB, 16, 2), 256, 0, stream>>>(
            h, wlT + (size_t)l*256*NH, rms_local + l*NH, alpha_local + l,
            nullptr, nullptr);
        k_mix2<16, true><<<dim3(NB, 16, 2), 256, 0, stream>>>(
            h, wgT + (size_t)l*256*NH, rms_global + l*NH, alpha_global + l,
            rms_ffn + l*NH, a_bf);
        k_mlp_in<<<dim3(16, 16), 256, 0, stream>>>(
            a_bf, wv_b + (size_t)l*NG*NH, wg_b + (size_t)l*NG*NH, g);
        k_mlp_out<<<dim3(16, 8), 256, 0, stream>>>(
            g, wo_b + (size_t)l*NH*NG, alpha_mlp + l, h);
    }
    k_norm2<<<512, 256, 0, stream>>>(h, head_rms, a_bf);
    k_head<<<dim3(32, 4), 256, 0, stream>>>(a_bf, head_wb, head_scale, out);
}